// Round 1
// baseline (314.078 us; speedup 1.0000x reference)
//
#include <hip/hip_runtime.h>

// ---------------------------------------------------------------------------
// TransformerBlock: B=2,S=2048,D=768,H=12,DH=64,DFF=3072, causal attn, 2x LN
// Round 14: attn_part rewritten with swapped QK^T (32x32x16 MFMA) + in-register
// softmax (T12: cvt_pk_bf16 + permlane32_swap). Removes the Ps LDS round-trip
// (32 ds_write_b16 + lgkmcnt(0) drain + 4 ds_read_b128 per tile per wave),
// removes the 4 ones-MFMAs (l-sum now VALU adds + shfl_xor 32), LDS 51.2->32KB
// so 4 blocks/CU and the whole 960-block grid is co-resident.
// GEMM = R10 proven structure (BK=64, two barriers, staging-source XOR swizzle).
// ---------------------------------------------------------------------------

typedef __attribute__((ext_vector_type(8)))  short    short8;    // 8 x bf16 (4 VGPR)
typedef __attribute__((ext_vector_type(4)))  float    floatx4;   // 4 x f32 acc
typedef __attribute__((ext_vector_type(16))) float    floatx16;  // 16 x f32 acc (32x32)
typedef __attribute__((ext_vector_type(4)))  unsigned uint4v;

#define QSC 0.18033688f   // 0.125 * log2(e): folded into Q at scatter
#define C2  24.0f         // fixed base-2 softmax offset

__device__ __forceinline__ float b2f(unsigned short u) {
    return __uint_as_float(((unsigned)u) << 16);
}
__device__ __forceinline__ unsigned short f2b(float f) {  // RNE
    unsigned x = __float_as_uint(f);
    return (unsigned short)((x + 0x7fffu + ((x >> 16) & 1u)) >> 16);
}
__device__ __forceinline__ void async_cp16(const void* g, void* l) {
    __builtin_amdgcn_global_load_lds((const __attribute__((address_space(1))) void*)g,
                                     (__attribute__((address_space(3))) void*)l,
                                     16, 0, 0);
}
// pack two f32 -> one dword of 2 x bf16 (RNE); lo = first arg
__device__ __forceinline__ unsigned cvtpk(float lo, float hi) {
    unsigned r;
    asm("v_cvt_pk_bf16_f32 %0, %1, %2" : "=v"(r) : "v"(lo), "v"(hi));
    return r;
}
// swap upper 32 lanes of a with lower 32 lanes of b (both updated)
__device__ __forceinline__ void plswap(unsigned& a, unsigned& b) {
    asm("v_permlane32_swap_b32 %0, %1" : "+v"(a), "+v"(b));
}
// chunk-slot prefix for 512-wide kv chunks: ofs(qb) = sum_{j<qb} ceil((j+1)/4)
//   = (t+1)*(2t+rem), t = qb>>2, rem = qb&3.  ofs(16) = 40 slots per bh.
__device__ __forceinline__ int chunk_ofs8(int qb) {
    int t = qb >> 2, rem = qb & 3;
    return (t + 1) * (2 * t + rem);
}
// XOR-swizzled [R][64] bf16 tile: elem offset of logical 16B chunk `chunk`
__device__ __forceinline__ int swz16(int row, int chunk) {
    return row * 64 + (((chunk ^ (row & 7)) & 7) << 3);
}

// ---------------- fused prepass: x->bf16 + 4 weight transposes --------------
__global__ __launch_bounds__(256) void prep_all(
    const float* __restrict__ x,    unsigned short* __restrict__ xb,
    const float* __restrict__ Wqkv, unsigned short* __restrict__ wqkvT,
    const float* __restrict__ Wout, unsigned short* __restrict__ woutT,
    const float* __restrict__ W1,   unsigned short* __restrict__ w1T,
    const float* __restrict__ W2,   unsigned short* __restrict__ w2T)
{
    __shared__ float tile[32][33];
    int idx = blockIdx.x;
    int tx = threadIdx.x & 31, ty = threadIdx.x >> 5;
    if (idx >= 6912) {  // cvt x
        int i = (idx - 6912) * 256 + threadIdx.x;
        float4 v = ((const float4*)x)[i];
        ushort4 u;
        u.x = f2b(v.x); u.y = f2b(v.y); u.z = f2b(v.z); u.w = f2b(v.w);
        ((ushort4*)xb)[i] = u;
        return;
    }
    const float* W; unsigned short* Wt; int K, N, bx, by;
    if (idx < 1728)      { W = Wqkv; Wt = wqkvT; K = 768;  N = 2304; bx = idx % 72;        by = idx / 72; }
    else if (idx < 2304) { W = Wout; Wt = woutT; K = 768;  N = 768;  bx = (idx-1728) % 24; by = (idx-1728) / 24; }
    else if (idx < 4608) { W = W1;   Wt = w1T;   K = 768;  N = 3072; bx = (idx-2304) % 96; by = (idx-2304) / 96; }
    else                 { W = W2;   Wt = w2T;   K = 3072; N = 768;  bx = (idx-4608) % 24; by = (idx-4608) / 24; }
    int n0 = bx * 32, k0 = by * 32;
    for (int i = ty; i < 32; i += 8)
        tile[i][tx] = W[(size_t)(k0 + i) * N + n0 + tx];
    __syncthreads();
    for (int i = ty; i < 32; i += 8)
        Wt[(size_t)(n0 + i) * K + k0 + tx] = f2b(tile[tx][i]);
}

// ---------------- bf16 MFMA GEMM (BK=64, swizzled LDS) -----------------------
// mode 0: row-major outF/outB (+bias, relu)
// mode 1: qkv scatter -> outB = Q|K|V each [24][2048][64]; Q scaled by QSC
// mode 2: split-K fp32 partial -> outF + blockIdx.z*M*N
__global__ __launch_bounds__(256) void gemm_bf16(
    const unsigned short* __restrict__ A,
    const unsigned short* __restrict__ Bt,
    const float* __restrict__ bias,
    float* __restrict__ outF,
    unsigned short* __restrict__ outB,
    int M, int N, int K, int relu, int mode, int kslab)
{
    __shared__ unsigned short As[8192];   // swizzled [128][64]
    __shared__ unsigned short Bs[8192];
    const int tid  = threadIdx.x;
    const int m0   = blockIdx.y * 128;
    const int n0   = blockIdx.x * 128;
    const int kz   = blockIdx.z;
    const int kbeg = kz * kslab;
    const int kend = kbeg + kslab;
    const int lane = tid & 63;
    const int wave = tid >> 6;
    const int wm   = (wave >> 1) * 64;
    const int wn   = (wave & 1) * 64;
    const int fr   = lane & 15;
    const int fq   = lane >> 4;

    floatx4 acc[4][4];
    for (int i = 0; i < 4; i++)
        for (int j = 0; j < 4; j++)
            for (int e = 0; e < 4; e++) acc[i][j][e] = 0.f;

    for (int kk = kbeg; kk < kend; kk += 64) {
        __syncthreads();
        #pragma unroll
        for (int r = 0; r < 4; ++r) {
            int c   = r * 256 + tid;          // LDS dest chunk (lane-contig)
            int row = c >> 3;
            int jj  = ((c & 7) ^ (row & 7)) * 8;  // swizzled global source col
            async_cp16(A  + (size_t)(m0 + row) * K + kk + jj, &As[c * 8]);
            async_cp16(Bt + (size_t)(n0 + row) * K + kk + jj, &Bs[c * 8]);
        }
        __syncthreads();

        #pragma unroll
        for (int kc = 0; kc < 2; ++kc) {
            short8 a[4], b[4];
            #pragma unroll
            for (int t = 0; t < 4; t++) a[t] = *(const short8*)&As[swz16(wm + t * 16 + fr, kc * 4 + fq)];
            #pragma unroll
            for (int t = 0; t < 4; t++) b[t] = *(const short8*)&Bs[swz16(wn + t * 16 + fr, kc * 4 + fq)];
            #pragma unroll
            for (int i = 0; i < 4; i++)
                #pragma unroll
                for (int j = 0; j < 4; j++)
                    acc[i][j] = __builtin_amdgcn_mfma_f32_16x16x32_bf16(a[i], b[j], acc[i][j], 0, 0, 0);
        }
    }

    if (mode == 2) {
        float* dst = outF + (size_t)kz * M * N;
        #pragma unroll
        for (int j = 0; j < 4; j++) {
            int col = n0 + wn + j * 16 + fr;
            #pragma unroll
            for (int i = 0; i < 4; i++) {
                int rbase = m0 + wm + i * 16 + fq * 4;
                #pragma unroll
                for (int e = 0; e < 4; e++)
                    dst[(size_t)(rbase + e) * N + col] = acc[i][j][e];
            }
        }
        return;
    }
    if (mode == 1) {
        #pragma unroll
        for (int j = 0; j < 4; j++) {
            int col   = n0 + wn + j * 16 + fr;
            int which = (col >= 1536) ? 2 : (col >= 768 ? 1 : 0);
            float sc  = (which == 0) ? QSC : 1.0f;   // fold 0.125*log2e into Q
            int rem   = col - which * 768;
            int hh    = rem >> 6, d = rem & 63;
            #pragma unroll
            for (int i = 0; i < 4; i++) {
                int rbase = m0 + wm + i * 16 + fq * 4;
                #pragma unroll
                for (int e = 0; e < 4; e++) {
                    int row = rbase + e;
                    int b_  = row >> 11, srow = row & 2047;
                    size_t idx = (size_t)which * 3145728 +
                                 ((size_t)(b_ * 12 + hh) * 2048 + srow) * 64 + d;
                    outB[idx] = f2b(acc[i][j][e] * sc);
                }
            }
        }
        return;
    }
    #pragma unroll
    for (int j = 0; j < 4; j++) {
        int col  = n0 + wn + j * 16 + fr;
        float bv = bias ? bias[col] : 0.f;
        #pragma unroll
        for (int i = 0; i < 4; i++) {
            int rbase = m0 + wm + i * 16 + fq * 4;
            #pragma unroll
            for (int e = 0; e < 4; e++) {
                float v = acc[i][j][e] + bv;
                if (relu) v = fmaxf(v, 0.f);
                size_t idx = (size_t)(rbase + e) * N + col;
                if (outF) outF[idx] = v;
                if (outB) outB[idx] = f2b(v);
            }
        }
    }
}

// ---------------- attention partial (512-wide kv chunks) --------------------
// grid (40, 24): slot r in [0,40) per bh; qb s.t. ofs8(qb) <= r < ofs8(qb+1),
// c = r - ofs8(qb). Tiles [8c, min(8c+8, 2qb+2)).
// Swapped QK^T with 32x32x16 MFMA: s^T col = lane&31 = q, so each lane pair
// (l, l^32) holds a full P row -> softmax + P->bf16 A-frag build fully
// in-register (cvt_pk + permlane32_swap), no Ps LDS buffer, no lgkm drain.
// l-sum = per-lane f32 adds + shfl_xor(32). LDS 32KB -> 4 blocks/CU.
__global__ __launch_bounds__(256, 4) void attn_part(const unsigned short* __restrict__ Qg,
                                                    const unsigned short* __restrict__ Kg,
                                                    const unsigned short* __restrict__ Vg,
                                                    unsigned short* __restrict__ pO,
                                                    float* __restrict__ pL) {
    __shared__ unsigned short Ks[2][4096];   // [64 kv][64 d] swizzled
    __shared__ unsigned short Vt[2][4096];   // [64 d][64 kv] swizzled (V^T)
    const int tid  = threadIdx.x;
    const int lane = tid & 63;
    const int wave = tid >> 6;
    const int ql   = lane & 31;          // this lane's q row within wave block
    const int hi   = lane >> 5;
    const int wm   = wave * 32;          // wave's 32-row q block
    const int r    = 39 - blockIdx.x;    // longest chunks first
    const int bh   = blockIdx.y;
    int qb = 0;
    for (int q_ = 15; q_ >= 0; --q_) if (r >= chunk_ofs8(q_)) { qb = q_; break; }
    const int c     = r - chunk_ofs8(qb);
    const int q0    = qb * 128;
    const int tile0 = 8 * c;
    const int ntk   = min(8, 2 * (qb + 1) - 8 * c);
    const int slot  = bh * 40 + r;
    const unsigned short* Qb = Qg + (size_t)bh * 131072;
    const unsigned short* Kb = Kg + (size_t)bh * 131072;
    const unsigned short* Vb = Vg + (size_t)bh * 131072;
    const int qrow = q0 + wm + ql;       // this lane's global q row

    // Q B-frags: col = q = ql, k = 16*c4 + 8*hi + j
    short8 qf[4];
    {
        const unsigned short* qr = Qb + (size_t)qrow * 64 + hi * 8;
        #pragma unroll
        for (int c4 = 0; c4 < 4; ++c4)
            qf[c4] = *(const short8*)(qr + c4 * 16);
    }

    floatx16 o[2];
    #pragma unroll
    for (int db = 0; db < 2; ++db)
        #pragma unroll
        for (int e = 0; e < 16; ++e) o[db][e] = 0.f;
    float ls[4] = {0.f, 0.f, 0.f, 0.f};

    const int c0 = tid, c1 = tid + 256;
    uint4 kr0, kr1, vr0, vr1;

#define LOADT(TG)                                                              \
    {                                                                          \
        int base = (TG) * 64;                                                  \
        kr0 = *(const uint4*)(Kb + (size_t)(base + (c0 >> 3)) * 64 + (c0 & 7) * 8); \
        kr1 = *(const uint4*)(Kb + (size_t)(base + (c1 >> 3)) * 64 + (c1 & 7) * 8); \
        vr0 = *(const uint4*)(Vb + (size_t)(base + (c0 & 63)) * 64 + (c0 >> 6) * 8); \
        vr1 = *(const uint4*)(Vb + (size_t)(base + (c1 & 63)) * 64 + (c1 >> 6) * 8); \
    }
// Vt transposed write: row = (c>>6)*8 + i (so row&7 == i), col = c&63
#define WRITET(BUF)                                                            \
    {                                                                          \
        *(uint4*)&Ks[BUF][swz16(c0 >> 3, c0 & 7)] = kr0;                       \
        *(uint4*)&Ks[BUF][swz16(c1 >> 3, c1 & 7)] = kr1;                       \
        unsigned short t0[8]; *(uint4*)t0 = vr0;                               \
        _Pragma("unroll") for (int i_ = 0; i_ < 8; ++i_)                       \
            Vt[BUF][((c0 >> 6) * 8 + i_) * 64 +                                \
                    (((((c0 >> 3) & 7) ^ i_) << 3) | (c0 & 7))] = t0[i_];      \
        unsigned short t1[8]; *(uint4*)t1 = vr1;                               \
        _Pragma("unroll") for (int i_ = 0; i_ < 8; ++i_)                       \
            Vt[BUF][((c1 >> 6) * 8 + i_) * 64 +                                \
                    (((((c1 >> 3) & 7) ^ i_) << 3) | (c1 & 7))] = t1[i_];      \
    }

    LOADT(tile0);
    WRITET(0);
    __syncthreads();

    for (int kt = 0; kt < ntk; ++kt) {
        const int  tg   = tile0 + kt;
        const int  cur  = kt & 1;
        const bool more = (kt + 1 < ntk);
        if (more) LOADT(tg + 1);

        #pragma unroll
        for (int bb = 0; bb < 2; ++bb) {
            // ---- QK^T (swapped): s^T[kv][q], A = K rows, B = Q cols ----
            short8 kf[4];
            #pragma unroll
            for (int c4 = 0; c4 < 4; ++c4)
                kf[c4] = *(const short8*)&Ks[cur][swz16(32 * bb + ql, 2 * c4 + hi)];
            floatx16 s;
            #pragma unroll
            for (int e = 0; e < 16; ++e) s[e] = 0.f;
            #pragma unroll
            for (int c4 = 0; c4 < 4; ++c4)
                s = __builtin_amdgcn_mfma_f32_32x32x16_bf16(kf[c4], qf[c4], s, 0, 0, 0);

            // ---- softmax: p = 2^(s - C2); causal mask -> 0 ----
            // lane's kv for reg e: kvb + (e&3) + 8*(e>>2)
            const int  kvb = tg * 64 + 32 * bb + 4 * hi;
            const bool nm  = (tg * 64 + 32 * bb + 31) > (q0 + wm);
            if (nm) {
                #pragma unroll
                for (int e = 0; e < 16; ++e)
                    if (kvb + (e & 3) + 8 * (e >> 2) > qrow) s[e] = -1e30f;
            }
            float pv[16];
            #pragma unroll
            for (int e = 0; e < 16; ++e) {
                pv[e] = __builtin_amdgcn_exp2f(s[e] - C2);
                ls[e & 3] += pv[e];
            }

            // ---- P -> bf16 A-frags in-register ----
            // word(m,w') = pack(pv[4m+2w'], pv[4m+2w'+1]) carries kv 8m+4hi+2w';
            // one permlane32_swap yields frag words w and w+2 for all lanes.
            unsigned w[8];
            #pragma unroll
            for (int m = 0; m < 4; ++m) {
                w[2 * m]     = cvtpk(pv[4 * m],     pv[4 * m + 1]);
                w[2 * m + 1] = cvtpk(pv[4 * m + 2], pv[4 * m + 3]);
            }
            plswap(w[0], w[2]);   // frag g=0: words 0,2
            plswap(w[1], w[3]);   // frag g=0: words 1,3
            plswap(w[4], w[6]);   // frag g=1: words 0,2
            plswap(w[5], w[7]);   // frag g=1: words 1,3
            uint4v u0 = {w[0], w[1], w[2], w[3]};
            uint4v u1 = {w[4], w[5], w[6], w[7]};
            short8 pa0 = __builtin_bit_cast(short8, u0);
            short8 pa1 = __builtin_bit_cast(short8, u1);

            // ---- PV: A = P frags, B = V^T (col = d, k = kv) ----
            #pragma unroll
            for (int db = 0; db < 2; ++db) {
                short8 vf0 = *(const short8*)&Vt[cur][swz16(32 * db + ql, 4 * bb + hi)];
                short8 vf1 = *(const short8*)&Vt[cur][swz16(32 * db + ql, 4 * bb + 2 + hi)];
                o[db] = __builtin_amdgcn_mfma_f32_32x32x16_bf16(pa0, vf0, o[db], 0, 0, 0);
                o[db] = __builtin_amdgcn_mfma_f32_32x32x16_bf16(pa1, vf1, o[db], 0, 0, 0);
            }
        }

        if (more) {
            WRITET(cur ^ 1);
            __syncthreads();
        }
    }
#undef LOADT
#undef WRITET

    float lsum = (ls[0] + ls[1]) + (ls[2] + ls[3]);
    lsum += __shfl_xor(lsum, 32);
    #pragma unroll
    for (int db = 0; db < 2; ++db)
        #pragma unroll
        for (int e = 0; e < 16; ++e) {
            int row = wm + (e & 3) + 8 * (e >> 2) + 4 * hi;
            pO[((size_t)slot * 128 + row) * 64 + db * 32 + ql] = f2b(o[db][e]);
        }
    if (lane < 32)
        pL[(size_t)slot * 128 + wm + ql] = lsum;
}

// ---------------- attention combine (fixed base: plain sums) ----------------
// grid (16, 24); merges <=4 chunks of 512 kv each.
__global__ __launch_bounds__(256) void attn_combine(const unsigned short* __restrict__ pO,
                                                    const float* __restrict__ pL,
                                                    unsigned short* __restrict__ ctx) {
    const int qb  = blockIdx.x;
    const int bh  = blockIdx.y;
    const int b   = bh / 12, h = bh % 12;
    const int nch = (qb >> 2) + 1;             // ceil((qb+1)/4)
    const int slot0 = bh * 40 + chunk_ofs8(qb);
    const int tid = threadIdx.x;
    const int row = tid >> 1;
    const int col0 = (tid & 1) * 32;

    float L = 0.f;
    for (int i = 0; i < nch; ++i)
        L += pL[(size_t)(slot0 + i) * 128 + row];

    float acc[32];
    #pragma unroll
    for (int j = 0; j < 32; ++j) acc[j] = 0.f;
    for (int i = 0; i < nch; ++i) {
        const unsigned short* p = pO + ((size_t)(slot0 + i) * 128 + row) * 64 + col0;
        #pragma unroll
        for (int v4 = 0; v4 < 4; ++v4) {
            uint4 u = *(const uint4*)(p + v4 * 8);
            unsigned short t[8]; *(uint4*)t = u;
            #pragma unroll
            for (int j = 0; j < 8; ++j) acc[v4 * 8 + j] += b2f(t[j]);
        }
    }
    float inv = 1.f / L;
    unsigned short* orow = ctx + ((size_t)(b * 2048 + qb * 128 + row)) * 768 + h * 64 + col0;
    #pragma unroll
    for (int v4 = 0; v4 < 4; ++v4) {
        unsigned short t[8];
        #pragma unroll
        for (int j = 0; j < 8; ++j) t[j] = f2b(acc[v4 * 8 + j] * inv);
        *(uint4*)(orow + v4 * 8) = *(uint4*)t;
    }
}

// ---------------- fused split-K reduce + bias + residual + LayerNorm --------
__global__ __launch_bounds__(256) void resid_ln2(const float* __restrict__ X,
                                                 const float* __restrict__ P,
                                                 int nsplit,
                                                 const float* __restrict__ bv,
                                                 const float* __restrict__ gain,
                                                 const float* __restrict__ beta,
                                                 float* __restrict__ outF,
                                                 unsigned short* __restrict__ outB) {
    const int row = blockIdx.x;
    const int t   = threadIdx.x;
    const size_t off = (size_t)row * 768;
    float v[3];
    #pragma unroll
    for (int i = 0; i < 3; i++) {
        size_t c = off + t + i * 256;
        float r = X[c] + bv[t + i * 256];
        for (int p = 0; p < nsplit; ++p) r += P[(size_t)p * 3145728 + c];
        v[i] = r;
    }
    float s  = v[0] + v[1] + v[2];
    float s2 = v[0] * v[0] + v[1] * v[1] + v[2] * v[2];
    #pragma unroll
    for (int o2 = 32; o2 > 0; o2 >>= 1) {
        s  += __shfl_down(s,  o2);
        s2 += __shfl_down(s2, o2);
    }
    __shared__ float rs[4], rq[4];
    if ((t & 63) == 0) { rs[t >> 6] = s; rq[t >> 6] = s2; }
    __syncthreads();
    float S    = rs[0] + rs[1] + rs[2] + rs[3];
    float S2   = rq[0] + rq[1] + rq[2] + rq[3];
    float mean = S * (1.0f / 768.0f);
    float var  = S2 * (1.0f / 768.0f) - mean * mean;
    float inv  = rsqrtf(var + 1e-5f);
    #pragma unroll
    for (int i = 0; i < 3; i++) {
        int c   = t + i * 256;
        float y = gain[c] * (v[i] - mean) * inv + beta[c];
        if (outF) outF[off + c] = y;
        if (outB) outB[off + c] = f2b(y);
    }
}

// ---------------------------------------------------------------------------
extern "C" void kernel_launch(void* const* d_in, const int* in_sizes, int n_in,
                              void* d_out, int out_size, void* d_ws, size_t ws_size,
                              hipStream_t stream) {
    const float* x    = (const float*)d_in[0];
    const float* Wqkv = (const float*)d_in[1];
    const float* Wout = (const float*)d_in[2];
    const float* bout = (const float*)d_in[3];
    const float* W1   = (const float*)d_in[4];
    const float* b1   = (const float*)d_in[5];
    const float* W2   = (const float*)d_in[6];
    const float* b2   = (const float*)d_in[7];
    const float* g1   = (const float*)d_in[8];
    const float* be1  = (const float*)d_in[9];
    const float* g2   = (const float*)d_in[10];
    const float* be2  = (const float*)d_in[11];
    float* out = (float*)d_out;

    // workspace layout (bytes), liveness-aliased; peak 83,361,792
    char* ws = (char*)d_ws;
    unsigned short* wqkvT  = (unsigned short*)(ws + 0);         // 3.5M  ->QKV
    unsigned short* woutT  = (unsigned short*)(ws + 3538944);   // 1.2M  ->Wout
    unsigned short* w1T    = (unsigned short*)(ws + 4718592);   // 4.7M  ->W1
    unsigned short* w2T    = (unsigned short*)(ws + 9437184);   // 4.7M  ->W2
    unsigned short* xb     = (unsigned short*)(ws + 14155776);  // 6.3M  ->QKV
    unsigned short* qkvG   = (unsigned short*)(ws + 20447232);  // 18.9M ->attn_part
    unsigned short* Qg     = qkvG;
    unsigned short* Kg     = qkvG + 3145728;
    unsigned short* Vg     = qkvG + 6291456;
    unsigned short* pO     = (unsigned short*)(ws + 39321600);  // 15.7M ->combine (960 slots)
    float*          pL     = (float*)(ws + 67633152);           // 0.49M ->combine
    unsigned short* ctxb   = (unsigned short*)(ws + 14155776);  // 6.3M  combine->Wout (xb dead)
    float*          WoutP  = (float*)(ws + 39321600);           // 3x12.6M Wout->LN1; ends 77,070,336
    float*          h      = (float*)(ws + 20447232);           // 12.6M LN1->LN2 (qkvG dead)
    unsigned short* hb     = (unsigned short*)(ws + 77070336);  // 6.3M  LN1->W1; ends 83,361,792
    unsigned short* ffb    = (unsigned short*)(ws + 39321600);  // 25.2M W1->W2 (WoutP dead)
    float*          W2P    = (float*)(ws + 64487424);           // 2x12.6M W2->LN2; ends 77,070,336

    // 1) fused prepass
    prep_all<<<9984, 256, 0, stream>>>(x, xb, Wqkv, wqkvT, Wout, woutT, W1, w1T, W2, w2T);
    // 2) QKV projection -> Q/K/V [bh][s][64] bf16 (Q pre-scaled by QSC)
    gemm_bf16<<<dim3(18, 32), 256, 0, stream>>>(xb, wqkvT, nullptr, nullptr, qkvG,
                                                4096, 2304, 768, 0, 1, 768);
    // 3) kv-split flash attention (512-wide chunks) + combine -> ctx bf16
    attn_part<<<dim3(40, 24), 256, 0, stream>>>(Qg, Kg, Vg, pO, pL);
    attn_combine<<<dim3(16, 24), 256, 0, stream>>>(pO, pL, ctxb);
    // 4) out projection, split-K=3 -> fp32 partials
    gemm_bf16<<<dim3(6, 32, 3), 256, 0, stream>>>(ctxb, woutT, nullptr, WoutP, nullptr,
                                                  4096, 768, 768, 0, 2, 256);
    // 5) h = LN(x + sum(WoutP) + bout) -> fp32 + bf16
    resid_ln2<<<4096, 256, 0, stream>>>(x, WoutP, 3, bout, g1, be1, h, hb);
    // 6) ff = relu(h @ W1 + b1) -> bf16
    gemm_bf16<<<dim3(24, 32), 256, 0, stream>>>(hb, w1T, b1, nullptr, ffb,
                                                4096, 3072, 768, 1, 0, 768);
    // 7) ff2 partials = ff @ W2 (split-K=2)
    gemm_bf16<<<dim3(6, 32, 2), 256, 0, stream>>>(ffb, w2T, nullptr, W2P, nullptr,
                                                  4096, 768, 3072, 0, 2, 1536);
    // 8) out = LN(h + sum(W2P) + b2) -> fp32
    resid_ln2<<<4096, 256, 0, stream>>>(h, W2P, 2, b2, g2, be2, out, nullptr);
}

// Round 2
// 311.360 us; speedup vs baseline: 1.0087x; 1.0087x over previous
//
#include <hip/hip_runtime.h>

// ---------------------------------------------------------------------------
// TransformerBlock: B=2,S=2048,D=768,H=12,DH=64,DFF=3072, causal attn, 2x LN
// Round 15: fix R14 regressions in attn_part.
//  (a) pO epilogue: restage o through dead Ks LDS -> full-line uint4 stores
//      (R14's 2B scatter caused 4x HBM write amplification: 65MB vs 15.7MB).
//  (b) Ks/Vt swizzle upgraded to perm(row)=(row&7)^((row>>2)&6): conflict-free
//      for rows=lane&31 reads under both consecutive AND stride-8 lane
//      groupings (R14's (row&7)-only XOR was 4-way under stride-8: 1.67M
//      conflict cycles).
//  (c) XCD-aware block remap (960=8*120): 3 bh per XCD -> K/V set 1.5MB in L2.
// Softmax stays fully in-register (swapped QK^T 32x32, cvt_pk+permlane32_swap).
// GEMM = R10 proven structure (BK=64, two barriers, staging-source XOR swizzle).
// ---------------------------------------------------------------------------

typedef __attribute__((ext_vector_type(8)))  short    short8;    // 8 x bf16 (4 VGPR)
typedef __attribute__((ext_vector_type(4)))  float    floatx4;   // 4 x f32 acc
typedef __attribute__((ext_vector_type(16))) float    floatx16;  // 16 x f32 acc (32x32)
typedef __attribute__((ext_vector_type(4)))  unsigned uint4v;

#define QSC 0.18033688f   // 0.125 * log2(e): folded into Q at scatter
#define C2  24.0f         // fixed base-2 softmax offset

__device__ __forceinline__ float b2f(unsigned short u) {
    return __uint_as_float(((unsigned)u) << 16);
}
__device__ __forceinline__ unsigned short f2b(float f) {  // RNE
    unsigned x = __float_as_uint(f);
    return (unsigned short)((x + 0x7fffu + ((x >> 16) & 1u)) >> 16);
}
__device__ __forceinline__ void async_cp16(const void* g, void* l) {
    __builtin_amdgcn_global_load_lds((const __attribute__((address_space(1))) void*)g,
                                     (__attribute__((address_space(3))) void*)l,
                                     16, 0, 0);
}
// pack two f32 -> one dword of 2 x bf16 (RNE); lo = first arg
__device__ __forceinline__ unsigned cvtpk(float lo, float hi) {
    unsigned r;
    asm("v_cvt_pk_bf16_f32 %0, %1, %2" : "=v"(r) : "v"(lo), "v"(hi));
    return r;
}
// swap upper 32 lanes of a with lower 32 lanes of b (both updated)
__device__ __forceinline__ void plswap(unsigned& a, unsigned& b) {
    asm("v_permlane32_swap_b32 %0, %1" : "+v"(a), "+v"(b));
}
// chunk-slot prefix for 512-wide kv chunks: ofs(qb) = sum_{j<qb} ceil((j+1)/4)
__device__ __forceinline__ int chunk_ofs8(int qb) {
    int t = qb >> 2, rem = qb & 3;
    return (t + 1) * (2 * t + rem);
}
// GEMM XOR-swizzled [R][64] bf16 tile (16-row x 4-chunk read groups: 2-way max)
__device__ __forceinline__ int swz16(int row, int chunk) {
    return row * 64 + (((chunk ^ (row & 7)) & 7) << 3);
}
// attn swizzle: rows=lane&31 reads need perm varying in row>>3 too
__device__ __forceinline__ int swzB(int row, int chunk) {
    return row * 64 + (((chunk ^ (row & 7) ^ ((row >> 2) & 6)) & 7) << 3);
}

// ---------------- fused prepass: x->bf16 + 4 weight transposes --------------
__global__ __launch_bounds__(256) void prep_all(
    const float* __restrict__ x,    unsigned short* __restrict__ xb,
    const float* __restrict__ Wqkv, unsigned short* __restrict__ wqkvT,
    const float* __restrict__ Wout, unsigned short* __restrict__ woutT,
    const float* __restrict__ W1,   unsigned short* __restrict__ w1T,
    const float* __restrict__ W2,   unsigned short* __restrict__ w2T)
{
    __shared__ float tile[32][33];
    int idx = blockIdx.x;
    int tx = threadIdx.x & 31, ty = threadIdx.x >> 5;
    if (idx >= 6912) {  // cvt x
        int i = (idx - 6912) * 256 + threadIdx.x;
        float4 v = ((const float4*)x)[i];
        ushort4 u;
        u.x = f2b(v.x); u.y = f2b(v.y); u.z = f2b(v.z); u.w = f2b(v.w);
        ((ushort4*)xb)[i] = u;
        return;
    }
    const float* W; unsigned short* Wt; int K, N, bx, by;
    if (idx < 1728)      { W = Wqkv; Wt = wqkvT; K = 768;  N = 2304; bx = idx % 72;        by = idx / 72; }
    else if (idx < 2304) { W = Wout; Wt = woutT; K = 768;  N = 768;  bx = (idx-1728) % 24; by = (idx-1728) / 24; }
    else if (idx < 4608) { W = W1;   Wt = w1T;   K = 768;  N = 3072; bx = (idx-2304) % 96; by = (idx-2304) / 96; }
    else                 { W = W2;   Wt = w2T;   K = 3072; N = 768;  bx = (idx-4608) % 24; by = (idx-4608) / 24; }
    int n0 = bx * 32, k0 = by * 32;
    for (int i = ty; i < 32; i += 8)
        tile[i][tx] = W[(size_t)(k0 + i) * N + n0 + tx];
    __syncthreads();
    for (int i = ty; i < 32; i += 8)
        Wt[(size_t)(n0 + i) * K + k0 + tx] = f2b(tile[tx][i]);
}

// ---------------- bf16 MFMA GEMM (BK=64, swizzled LDS) -----------------------
// mode 0: row-major outF/outB (+bias, relu)
// mode 1: qkv scatter -> outB = Q|K|V each [24][2048][64]; Q scaled by QSC
// mode 2: split-K fp32 partial -> outF + blockIdx.z*M*N
__global__ __launch_bounds__(256) void gemm_bf16(
    const unsigned short* __restrict__ A,
    const unsigned short* __restrict__ Bt,
    const float* __restrict__ bias,
    float* __restrict__ outF,
    unsigned short* __restrict__ outB,
    int M, int N, int K, int relu, int mode, int kslab)
{
    __shared__ unsigned short As[8192];   // swizzled [128][64]
    __shared__ unsigned short Bs[8192];
    const int tid  = threadIdx.x;
    const int m0   = blockIdx.y * 128;
    const int n0   = blockIdx.x * 128;
    const int kz   = blockIdx.z;
    const int kbeg = kz * kslab;
    const int kend = kbeg + kslab;
    const int lane = tid & 63;
    const int wave = tid >> 6;
    const int wm   = (wave >> 1) * 64;
    const int wn   = (wave & 1) * 64;
    const int fr   = lane & 15;
    const int fq   = lane >> 4;

    floatx4 acc[4][4];
    for (int i = 0; i < 4; i++)
        for (int j = 0; j < 4; j++)
            for (int e = 0; e < 4; e++) acc[i][j][e] = 0.f;

    for (int kk = kbeg; kk < kend; kk += 64) {
        __syncthreads();
        #pragma unroll
        for (int r = 0; r < 4; ++r) {
            int c   = r * 256 + tid;          // LDS dest chunk (lane-contig)
            int row = c >> 3;
            int jj  = ((c & 7) ^ (row & 7)) * 8;  // swizzled global source col
            async_cp16(A  + (size_t)(m0 + row) * K + kk + jj, &As[c * 8]);
            async_cp16(Bt + (size_t)(n0 + row) * K + kk + jj, &Bs[c * 8]);
        }
        __syncthreads();

        #pragma unroll
        for (int kc = 0; kc < 2; ++kc) {
            short8 a[4], b[4];
            #pragma unroll
            for (int t = 0; t < 4; t++) a[t] = *(const short8*)&As[swz16(wm + t * 16 + fr, kc * 4 + fq)];
            #pragma unroll
            for (int t = 0; t < 4; t++) b[t] = *(const short8*)&Bs[swz16(wn + t * 16 + fr, kc * 4 + fq)];
            #pragma unroll
            for (int i = 0; i < 4; i++)
                #pragma unroll
                for (int j = 0; j < 4; j++)
                    acc[i][j] = __builtin_amdgcn_mfma_f32_16x16x32_bf16(a[i], b[j], acc[i][j], 0, 0, 0);
        }
    }

    if (mode == 2) {
        float* dst = outF + (size_t)kz * M * N;
        #pragma unroll
        for (int j = 0; j < 4; j++) {
            int col = n0 + wn + j * 16 + fr;
            #pragma unroll
            for (int i = 0; i < 4; i++) {
                int rbase = m0 + wm + i * 16 + fq * 4;
                #pragma unroll
                for (int e = 0; e < 4; e++)
                    dst[(size_t)(rbase + e) * N + col] = acc[i][j][e];
            }
        }
        return;
    }
    if (mode == 1) {
        #pragma unroll
        for (int j = 0; j < 4; j++) {
            int col   = n0 + wn + j * 16 + fr;
            int which = (col >= 1536) ? 2 : (col >= 768 ? 1 : 0);
            float sc  = (which == 0) ? QSC : 1.0f;   // fold 0.125*log2e into Q
            int rem   = col - which * 768;
            int hh    = rem >> 6, d = rem & 63;
            #pragma unroll
            for (int i = 0; i < 4; i++) {
                int rbase = m0 + wm + i * 16 + fq * 4;
                #pragma unroll
                for (int e = 0; e < 4; e++) {
                    int row = rbase + e;
                    int b_  = row >> 11, srow = row & 2047;
                    size_t idx = (size_t)which * 3145728 +
                                 ((size_t)(b_ * 12 + hh) * 2048 + srow) * 64 + d;
                    outB[idx] = f2b(acc[i][j][e] * sc);
                }
            }
        }
        return;
    }
    #pragma unroll
    for (int j = 0; j < 4; j++) {
        int col  = n0 + wn + j * 16 + fr;
        float bv = bias ? bias[col] : 0.f;
        #pragma unroll
        for (int i = 0; i < 4; i++) {
            int rbase = m0 + wm + i * 16 + fq * 4;
            #pragma unroll
            for (int e = 0; e < 4; e++) {
                float v = acc[i][j][e] + bv;
                if (relu) v = fmaxf(v, 0.f);
                size_t idx = (size_t)(rbase + e) * N + col;
                if (outF) outF[idx] = v;
                if (outB) outB[idx] = f2b(v);
            }
        }
    }
}

// ---------------- attention partial (512-wide kv chunks) --------------------
// grid (40, 24) remapped XCD-aware: work id swz=(bid&7)*120+(bid>>3) so each
// XCD owns 3 whole bh (K/V 1.5MB -> L2 resident). Per slot: qb from prefix,
// tiles [8c, min(8c+8, 2qb+2)). Swapped QK^T (32x32x16), softmax in-register
// (cvt_pk + permlane32_swap), l-sum = VALU + shfl_xor(32). Epilogue restages
// o via LDS for full-line uint4 pO stores. LDS 32KB -> 4 blocks/CU.
__global__ __launch_bounds__(256, 4) void attn_part(const unsigned short* __restrict__ Qg,
                                                    const unsigned short* __restrict__ Kg,
                                                    const unsigned short* __restrict__ Vg,
                                                    unsigned short* __restrict__ pO,
                                                    float* __restrict__ pL) {
    __shared__ unsigned short Ks[2][4096];   // [64 kv][64 d] swzB
    __shared__ unsigned short Vt[2][4096];   // [64 d][64 kv] swzB (V^T)
    const int tid  = threadIdx.x;
    const int lane = tid & 63;
    const int wave = tid >> 6;
    const int ql   = lane & 31;          // q row within wave block (MFMA col)
    const int hi   = lane >> 5;
    const int wm   = wave * 32;          // wave's 32-row q block
    const int bid  = blockIdx.y * 40 + blockIdx.x;
    const int swz  = (bid & 7) * 120 + (bid >> 3);   // 960 = 8*120, bijective
    const int bh   = swz / 40;
    const int r    = 39 - (swz % 40);    // longest chunks first per XCD
    int qb = 0;
    for (int q_ = 15; q_ >= 0; --q_) if (r >= chunk_ofs8(q_)) { qb = q_; break; }
    const int c     = r - chunk_ofs8(qb);
    const int q0    = qb * 128;
    const int tile0 = 8 * c;
    const int ntk   = min(8, 2 * (qb + 1) - 8 * c);
    const int slot  = bh * 40 + r;
    const unsigned short* Qb = Qg + (size_t)bh * 131072;
    const unsigned short* Kb = Kg + (size_t)bh * 131072;
    const unsigned short* Vb = Vg + (size_t)bh * 131072;
    const int qrow = q0 + wm + ql;       // this lane's global q row

    // Q B-frags: col = q = ql, k = 16*c4 + 8*hi + j
    short8 qf[4];
    {
        const unsigned short* qr = Qb + (size_t)qrow * 64 + hi * 8;
        #pragma unroll
        for (int c4 = 0; c4 < 4; ++c4)
            qf[c4] = *(const short8*)(qr + c4 * 16);
    }

    floatx16 o[2];
    #pragma unroll
    for (int db = 0; db < 2; ++db)
        #pragma unroll
        for (int e = 0; e < 16; ++e) o[db][e] = 0.f;
    float ls[4] = {0.f, 0.f, 0.f, 0.f};

    const int c0 = tid, c1 = tid + 256;
    uint4 kr0, kr1, vr0, vr1;

#define LOADT(TG)                                                              \
    {                                                                          \
        int base = (TG) * 64;                                                  \
        kr0 = *(const uint4*)(Kb + (size_t)(base + (c0 >> 3)) * 64 + (c0 & 7) * 8); \
        kr1 = *(const uint4*)(Kb + (size_t)(base + (c1 >> 3)) * 64 + (c1 & 7) * 8); \
        vr0 = *(const uint4*)(Vb + (size_t)(base + (c0 & 63)) * 64 + (c0 >> 6) * 8); \
        vr1 = *(const uint4*)(Vb + (size_t)(base + (c1 & 63)) * 64 + (c1 >> 6) * 8); \
    }
// Vt transposed write: logical (row=(c>>6)*8+i, kv=c&63), swzB element address
#define WRITET(BUF)                                                            \
    {                                                                          \
        *(uint4*)&Ks[BUF][swzB(c0 >> 3, c0 & 7)] = kr0;                       \
        *(uint4*)&Ks[BUF][swzB(c1 >> 3, c1 & 7)] = kr1;                       \
        unsigned short t0[8]; *(uint4*)t0 = vr0;                               \
        _Pragma("unroll") for (int i_ = 0; i_ < 8; ++i_) {                     \
            int rv = (c0 >> 6) * 8 + i_;                                       \
            Vt[BUF][rv * 64 + (((((c0 >> 3) & 7) ^ i_ ^ ((rv >> 2) & 6)) & 7) << 3) + (c0 & 7)] = t0[i_]; \
        }                                                                      \
        unsigned short t1[8]; *(uint4*)t1 = vr1;                               \
        _Pragma("unroll") for (int i_ = 0; i_ < 8; ++i_) {                     \
            int rv = (c1 >> 6) * 8 + i_;                                       \
            Vt[BUF][rv * 64 + (((((c1 >> 3) & 7) ^ i_ ^ ((rv >> 2) & 6)) & 7) << 3) + (c1 & 7)] = t1[i_]; \
        }                                                                      \
    }

    LOADT(tile0);
    WRITET(0);
    __syncthreads();

    for (int kt = 0; kt < ntk; ++kt) {
        const int  tg   = tile0 + kt;
        const int  cur  = kt & 1;
        const bool more = (kt + 1 < ntk);
        if (more) LOADT(tg + 1);

        #pragma unroll
        for (int bb = 0; bb < 2; ++bb) {
            // ---- QK^T (swapped): s^T[kv][q], A = K rows, B = Q cols ----
            short8 kf[4];
            #pragma unroll
            for (int c4 = 0; c4 < 4; ++c4)
                kf[c4] = *(const short8*)&Ks[cur][swzB(32 * bb + ql, 2 * c4 + hi)];
            floatx16 s;
            #pragma unroll
            for (int e = 0; e < 16; ++e) s[e] = 0.f;
            #pragma unroll
            for (int c4 = 0; c4 < 4; ++c4)
                s = __builtin_amdgcn_mfma_f32_32x32x16_bf16(kf[c4], qf[c4], s, 0, 0, 0);

            // ---- softmax: p = 2^(s - C2); causal mask -> 0 ----
            const int  kvb = tg * 64 + 32 * bb + 4 * hi;
            const bool nm  = (tg * 64 + 32 * bb + 31) > (q0 + wm);
            if (nm) {
                #pragma unroll
                for (int e = 0; e < 16; ++e)
                    if (kvb + (e & 3) + 8 * (e >> 2) > qrow) s[e] = -1e30f;
            }
            float pv[16];
            #pragma unroll
            for (int e = 0; e < 16; ++e) {
                pv[e] = __builtin_amdgcn_exp2f(s[e] - C2);
                ls[e & 3] += pv[e];
            }

            // ---- P -> bf16 A-frags in-register ----
            unsigned w[8];
            #pragma unroll
            for (int m = 0; m < 4; ++m) {
                w[2 * m]     = cvtpk(pv[4 * m],     pv[4 * m + 1]);
                w[2 * m + 1] = cvtpk(pv[4 * m + 2], pv[4 * m + 3]);
            }
            plswap(w[0], w[2]);   // frag g=0: words 0,2
            plswap(w[1], w[3]);   // frag g=0: words 1,3
            plswap(w[4], w[6]);   // frag g=1: words 0,2
            plswap(w[5], w[7]);   // frag g=1: words 1,3
            uint4v u0 = {w[0], w[1], w[2], w[3]};
            uint4v u1 = {w[4], w[5], w[6], w[7]};
            short8 pa0 = __builtin_bit_cast(short8, u0);
            short8 pa1 = __builtin_bit_cast(short8, u1);

            // ---- PV: A = P frags, B = V^T (col = d, k = kv) ----
            #pragma unroll
            for (int db = 0; db < 2; ++db) {
                short8 vf0 = *(const short8*)&Vt[cur][swzB(32 * db + ql, 4 * bb + hi)];
                short8 vf1 = *(const short8*)&Vt[cur][swzB(32 * db + ql, 4 * bb + 2 + hi)];
                o[db] = __builtin_amdgcn_mfma_f32_32x32x16_bf16(pa0, vf0, o[db], 0, 0, 0);
                o[db] = __builtin_amdgcn_mfma_f32_32x32x16_bf16(pa1, vf1, o[db], 0, 0, 0);
            }
        }

        if (more) {
            WRITET(cur ^ 1);
            __syncthreads();
        }
    }
#undef LOADT
#undef WRITET

    float lsum = (ls[0] + ls[1]) + (ls[2] + ls[3]);
    lsum += __shfl_xor(lsum, 32);

    // ---- epilogue: restage o (bf16) in dead Ks LDS, then full-line stores ----
    __syncthreads();                       // all waves done reading Ks/Vt
    unsigned short* Ost = &Ks[0][0];       // 16KB: [128][64], chunk ^ (row&7)
    #pragma unroll
    for (int db = 0; db < 2; ++db)
        #pragma unroll
        for (int e = 0; e < 16; ++e) {
            int row = wm + (e & 3) + 8 * (e >> 2) + 4 * hi;
            int col = db * 32 + ql;
            Ost[row * 64 + ((((col >> 3) ^ (row & 7)) & 7) << 3) + (col & 7)] =
                f2b(o[db][e]);
        }
    __syncthreads();
    #pragma unroll
    for (int p = 0; p < 4; ++p) {
        int chunk = p * 256 + tid;         // 1024 chunks = 128 rows x 8
        int row = chunk >> 3, cc = chunk & 7;
        uint4 val = *(const uint4*)&Ost[row * 64 + (((cc ^ (row & 7)) & 7) << 3)];
        *(uint4*)(pO + ((size_t)slot * 128 + row) * 64 + cc * 8) = val;
    }
    if (lane < 32)
        pL[(size_t)slot * 128 + wm + ql] = lsum;
}

// ---------------- attention combine (fixed base: plain sums) ----------------
// grid (16, 24); merges <=4 chunks of 512 kv each.
__global__ __launch_bounds__(256) void attn_combine(const unsigned short* __restrict__ pO,
                                                    const float* __restrict__ pL,
                                                    unsigned short* __restrict__ ctx) {
    const int qb  = blockIdx.x;
    const int bh  = blockIdx.y;
    const int b   = bh / 12, h = bh % 12;
    const int nch = (qb >> 2) + 1;             // ceil((qb+1)/4)
    const int slot0 = bh * 40 + chunk_ofs8(qb);
    const int tid = threadIdx.x;
    const int row = tid >> 1;
    const int col0 = (tid & 1) * 32;

    float L = 0.f;
    for (int i = 0; i < nch; ++i)
        L += pL[(size_t)(slot0 + i) * 128 + row];

    float acc[32];
    #pragma unroll
    for (int j = 0; j < 32; ++j) acc[j] = 0.f;
    for (int i = 0; i < nch; ++i) {
        const unsigned short* p = pO + ((size_t)(slot0 + i) * 128 + row) * 64 + col0;
        #pragma unroll
        for (int v4 = 0; v4 < 4; ++v4) {
            uint4 u = *(const uint4*)(p + v4 * 8);
            unsigned short t[8]; *(uint4*)t = u;
            #pragma unroll
            for (int j = 0; j < 8; ++j) acc[v4 * 8 + j] += b2f(t[j]);
        }
    }
    float inv = 1.f / L;
    unsigned short* orow = ctx + ((size_t)(b * 2048 + qb * 128 + row)) * 768 + h * 64 + col0;
    #pragma unroll
    for (int v4 = 0; v4 < 4; ++v4) {
        unsigned short t[8];
        #pragma unroll
        for (int j = 0; j < 8; ++j) t[j] = f2b(acc[v4 * 8 + j] * inv);
        *(uint4*)(orow + v4 * 8) = *(uint4*)t;
    }
}

// ---------------- fused split-K reduce + bias + residual + LayerNorm --------
__global__ __launch_bounds__(256) void resid_ln2(const float* __restrict__ X,
                                                 const float* __restrict__ P,
                                                 int nsplit,
                                                 const float* __restrict__ bv,
                                                 const float* __restrict__ gain,
                                                 const float* __restrict__ beta,
                                                 float* __restrict__ outF,
                                                 unsigned short* __restrict__ outB) {
    const int row = blockIdx.x;
    const int t   = threadIdx.x;
    const size_t off = (size_t)row * 768;
    float v[3];
    #pragma unroll
    for (int i = 0; i < 3; i++) {
        size_t c = off + t + i * 256;
        float r = X[c] + bv[t + i * 256];
        for (int p = 0; p < nsplit; ++p) r += P[(size_t)p * 3145728 + c];
        v[i] = r;
    }
    float s  = v[0] + v[1] + v[2];
    float s2 = v[0] * v[0] + v[1] * v[1] + v[2] * v[2];
    #pragma unroll
    for (int o2 = 32; o2 > 0; o2 >>= 1) {
        s  += __shfl_down(s,  o2);
        s2 += __shfl_down(s2, o2);
    }
    __shared__ float rs[4], rq[4];
    if ((t & 63) == 0) { rs[t >> 6] = s; rq[t >> 6] = s2; }
    __syncthreads();
    float S    = rs[0] + rs[1] + rs[2] + rs[3];
    float S2   = rq[0] + rq[1] + rq[2] + rq[3];
    float mean = S * (1.0f / 768.0f);
    float var  = S2 * (1.0f / 768.0f) - mean * mean;
    float inv  = rsqrtf(var + 1e-5f);
    #pragma unroll
    for (int i = 0; i < 3; i++) {
        int c   = t + i * 256;
        float y = gain[c] * (v[i] - mean) * inv + beta[c];
        if (outF) outF[off + c] = y;
        if (outB) outB[off + c] = f2b(y);
    }
}

// ---------------------------------------------------------------------------
extern "C" void kernel_launch(void* const* d_in, const int* in_sizes, int n_in,
                              void* d_out, int out_size, void* d_ws, size_t ws_size,
                              hipStream_t stream) {
    const float* x    = (const float*)d_in[0];
    const float* Wqkv = (const float*)d_in[1];
    const float* Wout = (const float*)d_in[2];
    const float* bout = (const float*)d_in[3];
    const float* W1   = (const float*)d_in[4];
    const float* b1   = (const float*)d_in[5];
    const float* W2   = (const float*)d_in[6];
    const float* b2   = (const float*)d_in[7];
    const float* g1   = (const float*)d_in[8];
    const float* be1  = (const float*)d_in[9];
    const float* g2   = (const float*)d_in[10];
    const float* be2  = (const float*)d_in[11];
    float* out = (float*)d_out;

    // workspace layout (bytes), liveness-aliased; peak 83,361,792
    char* ws = (char*)d_ws;
    unsigned short* wqkvT  = (unsigned short*)(ws + 0);         // 3.5M  ->QKV
    unsigned short* woutT  = (unsigned short*)(ws + 3538944);   // 1.2M  ->Wout
    unsigned short* w1T    = (unsigned short*)(ws + 4718592);   // 4.7M  ->W1
    unsigned short* w2T    = (unsigned short*)(ws + 9437184);   // 4.7M  ->W2
    unsigned short* xb     = (unsigned short*)(ws + 14155776);  // 6.3M  ->QKV
    unsigned short* qkvG   = (unsigned short*)(ws + 20447232);  // 18.9M ->attn_part
    unsigned short* Qg     = qkvG;
    unsigned short* Kg     = qkvG + 3145728;
    unsigned short* Vg     = qkvG + 6291456;
    unsigned short* pO     = (unsigned short*)(ws + 39321600);  // 15.7M ->combine (960 slots)
    float*          pL     = (float*)(ws + 67633152);           // 0.49M ->combine
    unsigned short* ctxb   = (unsigned short*)(ws + 14155776);  // 6.3M  combine->Wout (xb dead)
    float*          WoutP  = (float*)(ws + 39321600);           // 3x12.6M Wout->LN1; ends 77,070,336
    float*          h      = (float*)(ws + 20447232);           // 12.6M LN1->LN2 (qkvG dead)
    unsigned short* hb     = (unsigned short*)(ws + 77070336);  // 6.3M  LN1->W1; ends 83,361,792
    unsigned short* ffb    = (unsigned short*)(ws + 39321600);  // 25.2M W1->W2 (WoutP dead)
    float*          W2P    = (float*)(ws + 64487424);           // 2x12.6M W2->LN2; ends 77,070,336

    // 1) fused prepass
    prep_all<<<9984, 256, 0, stream>>>(x, xb, Wqkv, wqkvT, Wout, woutT, W1, w1T, W2, w2T);
    // 2) QKV projection -> Q/K/V [bh][s][64] bf16 (Q pre-scaled by QSC)
    gemm_bf16<<<dim3(18, 32), 256, 0, stream>>>(xb, wqkvT, nullptr, nullptr, qkvG,
                                                4096, 2304, 768, 0, 1, 768);
    // 3) kv-split flash attention (512-wide chunks) + combine -> ctx bf16
    attn_part<<<dim3(40, 24), 256, 0, stream>>>(Qg, Kg, Vg, pO, pL);
    attn_combine<<<dim3(16, 24), 256, 0, stream>>>(pO, pL, ctxb);
    // 4) out projection, split-K=3 -> fp32 partials
    gemm_bf16<<<dim3(6, 32, 3), 256, 0, stream>>>(ctxb, woutT, nullptr, WoutP, nullptr,
                                                  4096, 768, 768, 0, 2, 256);
    // 5) h = LN(x + sum(WoutP) + bout) -> fp32 + bf16
    resid_ln2<<<4096, 256, 0, stream>>>(x, WoutP, 3, bout, g1, be1, h, hb);
    // 6) ff = relu(h @ W1 + b1) -> bf16
    gemm_bf16<<<dim3(24, 32), 256, 0, stream>>>(hb, w1T, b1, nullptr, ffb,
                                                4096, 3072, 768, 1, 0, 768);
    // 7) ff2 partials = ff @ W2 (split-K=2)
    gemm_bf16<<<dim3(6, 32, 2), 256, 0, stream>>>(ffb, w2T, nullptr, W2P, nullptr,
                                                  4096, 768, 3072, 0, 2, 1536);
    // 8) out = LN(h + sum(W2P) + b2) -> fp32
    resid_ln2<<<4096, 256, 0, stream>>>(h, W2P, 2, b2, g2, be2, out, nullptr);
}

// Round 3
// 302.167 us; speedup vs baseline: 1.0394x; 1.0304x over previous
//
#include <hip/hip_runtime.h>

// ---------------------------------------------------------------------------
// TransformerBlock: B=2,S=2048,D=768,H=12,DH=64,DFF=3072, causal attn, 2x LN
// Round 16: GEMM K-loop -> double-buffered early-stage pipeline (T3 minimum
// 2-phase): STAGE(next tile) issued BEFORE compute(cur), ONE __syncthreads
// per K-step (implicit vmcnt(0) drain lands after ~500cy of MFMA+ds_read, so
// HBM/L2 latency is hidden). Old loop was stage->barrier->compute: latency
// fully exposed every K-step (MfmaUtil 12.6%, 340 TF on FFN1).
// Plus T1 bijective XCD block swizzle (m204): consecutive per-XCD ids share
// the A row-panel -> panels L2/L3-resident (FETCH was 3x ideal).
// attn_part = R15 (in-register softmax, swzB, LDS-restaged epilogue, XCD map).
// ---------------------------------------------------------------------------

typedef __attribute__((ext_vector_type(8)))  short    short8;    // 8 x bf16 (4 VGPR)
typedef __attribute__((ext_vector_type(4)))  float    floatx4;   // 4 x f32 acc
typedef __attribute__((ext_vector_type(16))) float    floatx16;  // 16 x f32 acc (32x32)
typedef __attribute__((ext_vector_type(4)))  unsigned uint4v;

#define QSC 0.18033688f   // 0.125 * log2(e): folded into Q at scatter
#define C2  24.0f         // fixed base-2 softmax offset

__device__ __forceinline__ float b2f(unsigned short u) {
    return __uint_as_float(((unsigned)u) << 16);
}
__device__ __forceinline__ unsigned short f2b(float f) {  // RNE
    unsigned x = __float_as_uint(f);
    return (unsigned short)((x + 0x7fffu + ((x >> 16) & 1u)) >> 16);
}
__device__ __forceinline__ void async_cp16(const void* g, void* l) {
    __builtin_amdgcn_global_load_lds((const __attribute__((address_space(1))) void*)g,
                                     (__attribute__((address_space(3))) void*)l,
                                     16, 0, 0);
}
// pack two f32 -> one dword of 2 x bf16 (RNE); lo = first arg
__device__ __forceinline__ unsigned cvtpk(float lo, float hi) {
    unsigned r;
    asm("v_cvt_pk_bf16_f32 %0, %1, %2" : "=v"(r) : "v"(lo), "v"(hi));
    return r;
}
// swap upper 32 lanes of a with lower 32 lanes of b (both updated)
__device__ __forceinline__ void plswap(unsigned& a, unsigned& b) {
    asm("v_permlane32_swap_b32 %0, %1" : "+v"(a), "+v"(b));
}
// chunk-slot prefix for 512-wide kv chunks: ofs(qb) = sum_{j<qb} ceil((j+1)/4)
__device__ __forceinline__ int chunk_ofs8(int qb) {
    int t = qb >> 2, rem = qb & 3;
    return (t + 1) * (2 * t + rem);
}
// GEMM XOR-swizzled [R][64] bf16 tile (16-row x 4-chunk read groups: 2-way max)
__device__ __forceinline__ int swz16(int row, int chunk) {
    return row * 64 + (((chunk ^ (row & 7)) & 7) << 3);
}
// attn swizzle: rows=lane&31 reads need perm varying in row>>3 too
__device__ __forceinline__ int swzB(int row, int chunk) {
    return row * 64 + (((chunk ^ (row & 7) ^ ((row >> 2) & 6)) & 7) << 3);
}

// ---------------- fused prepass: x->bf16 + 4 weight transposes --------------
__global__ __launch_bounds__(256) void prep_all(
    const float* __restrict__ x,    unsigned short* __restrict__ xb,
    const float* __restrict__ Wqkv, unsigned short* __restrict__ wqkvT,
    const float* __restrict__ Wout, unsigned short* __restrict__ woutT,
    const float* __restrict__ W1,   unsigned short* __restrict__ w1T,
    const float* __restrict__ W2,   unsigned short* __restrict__ w2T)
{
    __shared__ float tile[32][33];
    int idx = blockIdx.x;
    int tx = threadIdx.x & 31, ty = threadIdx.x >> 5;
    if (idx >= 6912) {  // cvt x
        int i = (idx - 6912) * 256 + threadIdx.x;
        float4 v = ((const float4*)x)[i];
        ushort4 u;
        u.x = f2b(v.x); u.y = f2b(v.y); u.z = f2b(v.z); u.w = f2b(v.w);
        ((ushort4*)xb)[i] = u;
        return;
    }
    const float* W; unsigned short* Wt; int K, N, bx, by;
    if (idx < 1728)      { W = Wqkv; Wt = wqkvT; K = 768;  N = 2304; bx = idx % 72;        by = idx / 72; }
    else if (idx < 2304) { W = Wout; Wt = woutT; K = 768;  N = 768;  bx = (idx-1728) % 24; by = (idx-1728) / 24; }
    else if (idx < 4608) { W = W1;   Wt = w1T;   K = 768;  N = 3072; bx = (idx-2304) % 96; by = (idx-2304) / 96; }
    else                 { W = W2;   Wt = w2T;   K = 3072; N = 768;  bx = (idx-4608) % 24; by = (idx-4608) / 24; }
    int n0 = bx * 32, k0 = by * 32;
    for (int i = ty; i < 32; i += 8)
        tile[i][tx] = W[(size_t)(k0 + i) * N + n0 + tx];
    __syncthreads();
    for (int i = ty; i < 32; i += 8)
        Wt[(size_t)(n0 + i) * K + k0 + tx] = f2b(tile[tx][i]);
}

// ---------------- bf16 MFMA GEMM (BK=64, swizzled LDS, dbuf pipeline) --------
// mode 0: row-major outF/outB (+bias, relu)
// mode 1: qkv scatter -> outB = Q|K|V each [24][2048][64]; Q scaled by QSC
// mode 2: split-K fp32 partial -> outF + blockIdx.z*M*N
__global__ __launch_bounds__(256) void gemm_bf16(
    const unsigned short* __restrict__ A,
    const unsigned short* __restrict__ Bt,
    const float* __restrict__ bias,
    float* __restrict__ outF,
    unsigned short* __restrict__ outB,
    int M, int N, int K, int relu, int mode, int kslab)
{
    __shared__ unsigned short As[2][8192];   // swizzled [128][64] x 2 (dbuf)
    __shared__ unsigned short Bs[2][8192];
    const int tid  = threadIdx.x;
    // T1: bijective XCD remap (m204). Row-major ids: consecutive per-XCD ids
    // share the A row-panel -> per-XCD L2 reuse.
    const int gx   = gridDim.x;
    const int nwg  = gx * gridDim.y;
    const int orig = blockIdx.y * gx + blockIdx.x;
    const int qch  = nwg >> 3, rem = nwg & 7;
    const int xcd  = orig & 7, sub = orig >> 3;
    const int nid  = (xcd < rem ? xcd * (qch + 1)
                                : rem * (qch + 1) + (xcd - rem) * qch) + sub;
    const int m0   = (nid / gx) * 128;
    const int n0   = (nid % gx) * 128;
    const int kz   = blockIdx.z;
    const int kbeg = kz * kslab;
    const int kend = kbeg + kslab;
    const int lane = tid & 63;
    const int wave = tid >> 6;
    const int wm   = (wave >> 1) * 64;
    const int wn   = (wave & 1) * 64;
    const int fr   = lane & 15;
    const int fq   = lane >> 4;

    floatx4 acc[4][4];
    for (int i = 0; i < 4; i++)
        for (int j = 0; j < 4; j++)
            for (int e = 0; e < 4; e++) acc[i][j][e] = 0.f;

#define STAGE(BUF, KK)                                                         \
    {                                                                          \
        _Pragma("unroll")                                                      \
        for (int r_ = 0; r_ < 4; ++r_) {                                       \
            int c_   = r_ * 256 + tid;       /* LDS dest chunk (lane-contig) */\
            int row_ = c_ >> 3;                                                \
            int jj_  = ((c_ & 7) ^ (row_ & 7)) * 8; /* swizzled global src  */ \
            async_cp16(A  + (size_t)(m0 + row_) * K + (KK) + jj_, &As[BUF][c_ * 8]); \
            async_cp16(Bt + (size_t)(n0 + row_) * K + (KK) + jj_, &Bs[BUF][c_ * 8]); \
        }                                                                      \
    }

    STAGE(0, kbeg);
    __syncthreads();                 // implicit vmcnt(0): tile0 in LDS
    int cur = 0;
    for (int kk = kbeg; kk < kend; kk += 64) {
        if (kk + 64 < kend) STAGE(cur ^ 1, kk + 64);   // loads fly under MFMA
        #pragma unroll
        for (int kc = 0; kc < 2; ++kc) {
            short8 a[4], b[4];
            #pragma unroll
            for (int t = 0; t < 4; t++) a[t] = *(const short8*)&As[cur][swz16(wm + t * 16 + fr, kc * 4 + fq)];
            #pragma unroll
            for (int t = 0; t < 4; t++) b[t] = *(const short8*)&Bs[cur][swz16(wn + t * 16 + fr, kc * 4 + fq)];
            #pragma unroll
            for (int i = 0; i < 4; i++)
                #pragma unroll
                for (int j = 0; j < 4; j++)
                    acc[i][j] = __builtin_amdgcn_mfma_f32_16x16x32_bf16(a[i], b[j], acc[i][j], 0, 0, 0);
        }
        __syncthreads();             // drains next-tile loads + all ds_reads
        cur ^= 1;
    }
#undef STAGE

    if (mode == 2) {
        float* dst = outF + (size_t)kz * M * N;
        #pragma unroll
        for (int j = 0; j < 4; j++) {
            int col = n0 + wn + j * 16 + fr;
            #pragma unroll
            for (int i = 0; i < 4; i++) {
                int rbase = m0 + wm + i * 16 + fq * 4;
                #pragma unroll
                for (int e = 0; e < 4; e++)
                    dst[(size_t)(rbase + e) * N + col] = acc[i][j][e];
            }
        }
        return;
    }
    if (mode == 1) {
        #pragma unroll
        for (int j = 0; j < 4; j++) {
            int col   = n0 + wn + j * 16 + fr;
            int which = (col >= 1536) ? 2 : (col >= 768 ? 1 : 0);
            float sc  = (which == 0) ? QSC : 1.0f;   // fold 0.125*log2e into Q
            int rem_  = col - which * 768;
            int hh    = rem_ >> 6, d = rem_ & 63;
            #pragma unroll
            for (int i = 0; i < 4; i++) {
                int rbase = m0 + wm + i * 16 + fq * 4;
                #pragma unroll
                for (int e = 0; e < 4; e++) {
                    int row = rbase + e;
                    int b_  = row >> 11, srow = row & 2047;
                    size_t idx = (size_t)which * 3145728 +
                                 ((size_t)(b_ * 12 + hh) * 2048 + srow) * 64 + d;
                    outB[idx] = f2b(acc[i][j][e] * sc);
                }
            }
        }
        return;
    }
    #pragma unroll
    for (int j = 0; j < 4; j++) {
        int col  = n0 + wn + j * 16 + fr;
        float bv = bias ? bias[col] : 0.f;
        #pragma unroll
        for (int i = 0; i < 4; i++) {
            int rbase = m0 + wm + i * 16 + fq * 4;
            #pragma unroll
            for (int e = 0; e < 4; e++) {
                float v = acc[i][j][e] + bv;
                if (relu) v = fmaxf(v, 0.f);
                size_t idx = (size_t)(rbase + e) * N + col;
                if (outF) outF[idx] = v;
                if (outB) outB[idx] = f2b(v);
            }
        }
    }
}

// ---------------- attention partial (512-wide kv chunks) --------------------
// grid (40, 24) remapped XCD-aware: work id swz=(bid&7)*120+(bid>>3) so each
// XCD owns 3 whole bh (K/V 1.5MB -> L2 resident). Per slot: qb from prefix,
// tiles [8c, min(8c+8, 2qb+2)). Swapped QK^T (32x32x16), softmax in-register
// (cvt_pk + permlane32_swap), l-sum = VALU + shfl_xor(32). Epilogue restages
// o via LDS for full-line uint4 pO stores. LDS 32KB -> 4 blocks/CU.
__global__ __launch_bounds__(256, 4) void attn_part(const unsigned short* __restrict__ Qg,
                                                    const unsigned short* __restrict__ Kg,
                                                    const unsigned short* __restrict__ Vg,
                                                    unsigned short* __restrict__ pO,
                                                    float* __restrict__ pL) {
    __shared__ unsigned short Ks[2][4096];   // [64 kv][64 d] swzB
    __shared__ unsigned short Vt[2][4096];   // [64 d][64 kv] swzB (V^T)
    const int tid  = threadIdx.x;
    const int lane = tid & 63;
    const int wave = tid >> 6;
    const int ql   = lane & 31;          // q row within wave block (MFMA col)
    const int hi   = lane >> 5;
    const int wm   = wave * 32;          // wave's 32-row q block
    const int bid  = blockIdx.y * 40 + blockIdx.x;
    const int swz  = (bid & 7) * 120 + (bid >> 3);   // 960 = 8*120, bijective
    const int bh   = swz / 40;
    const int r    = 39 - (swz % 40);    // longest chunks first per XCD
    int qb = 0;
    for (int q_ = 15; q_ >= 0; --q_) if (r >= chunk_ofs8(q_)) { qb = q_; break; }
    const int c     = r - chunk_ofs8(qb);
    const int q0    = qb * 128;
    const int tile0 = 8 * c;
    const int ntk   = min(8, 2 * (qb + 1) - 8 * c);
    const int slot  = bh * 40 + r;
    const unsigned short* Qb = Qg + (size_t)bh * 131072;
    const unsigned short* Kb = Kg + (size_t)bh * 131072;
    const unsigned short* Vb = Vg + (size_t)bh * 131072;
    const int qrow = q0 + wm + ql;       // this lane's global q row

    // Q B-frags: col = q = ql, k = 16*c4 + 8*hi + j
    short8 qf[4];
    {
        const unsigned short* qr = Qb + (size_t)qrow * 64 + hi * 8;
        #pragma unroll
        for (int c4 = 0; c4 < 4; ++c4)
            qf[c4] = *(const short8*)(qr + c4 * 16);
    }

    floatx16 o[2];
    #pragma unroll
    for (int db = 0; db < 2; ++db)
        #pragma unroll
        for (int e = 0; e < 16; ++e) o[db][e] = 0.f;
    float ls[4] = {0.f, 0.f, 0.f, 0.f};

    const int c0 = tid, c1 = tid + 256;
    uint4 kr0, kr1, vr0, vr1;

#define LOADT(TG)                                                              \
    {                                                                          \
        int base = (TG) * 64;                                                  \
        kr0 = *(const uint4*)(Kb + (size_t)(base + (c0 >> 3)) * 64 + (c0 & 7) * 8); \
        kr1 = *(const uint4*)(Kb + (size_t)(base + (c1 >> 3)) * 64 + (c1 & 7) * 8); \
        vr0 = *(const uint4*)(Vb + (size_t)(base + (c0 & 63)) * 64 + (c0 >> 6) * 8); \
        vr1 = *(const uint4*)(Vb + (size_t)(base + (c1 & 63)) * 64 + (c1 >> 6) * 8); \
    }
// Vt transposed write: logical (row=(c>>6)*8+i, kv=c&63), swzB element address
#define WRITET(BUF)                                                            \
    {                                                                          \
        *(uint4*)&Ks[BUF][swzB(c0 >> 3, c0 & 7)] = kr0;                       \
        *(uint4*)&Ks[BUF][swzB(c1 >> 3, c1 & 7)] = kr1;                       \
        unsigned short t0[8]; *(uint4*)t0 = vr0;                               \
        _Pragma("unroll") for (int i_ = 0; i_ < 8; ++i_) {                     \
            int rv = (c0 >> 6) * 8 + i_;                                       \
            Vt[BUF][rv * 64 + (((((c0 >> 3) & 7) ^ i_ ^ ((rv >> 2) & 6)) & 7) << 3) + (c0 & 7)] = t0[i_]; \
        }                                                                      \
        unsigned short t1[8]; *(uint4*)t1 = vr1;                               \
        _Pragma("unroll") for (int i_ = 0; i_ < 8; ++i_) {                     \
            int rv = (c1 >> 6) * 8 + i_;                                       \
            Vt[BUF][rv * 64 + (((((c1 >> 3) & 7) ^ i_ ^ ((rv >> 2) & 6)) & 7) << 3) + (c1 & 7)] = t1[i_]; \
        }                                                                      \
    }

    LOADT(tile0);
    WRITET(0);
    __syncthreads();

    for (int kt = 0; kt < ntk; ++kt) {
        const int  tg   = tile0 + kt;
        const int  cur  = kt & 1;
        const bool more = (kt + 1 < ntk);
        if (more) LOADT(tg + 1);

        #pragma unroll
        for (int bb = 0; bb < 2; ++bb) {
            // ---- QK^T (swapped): s^T[kv][q], A = K rows, B = Q cols ----
            short8 kf[4];
            #pragma unroll
            for (int c4 = 0; c4 < 4; ++c4)
                kf[c4] = *(const short8*)&Ks[cur][swzB(32 * bb + ql, 2 * c4 + hi)];
            floatx16 s;
            #pragma unroll
            for (int e = 0; e < 16; ++e) s[e] = 0.f;
            #pragma unroll
            for (int c4 = 0; c4 < 4; ++c4)
                s = __builtin_amdgcn_mfma_f32_32x32x16_bf16(kf[c4], qf[c4], s, 0, 0, 0);

            // ---- softmax: p = 2^(s - C2); causal mask -> 0 ----
            const int  kvb = tg * 64 + 32 * bb + 4 * hi;
            const bool nm  = (tg * 64 + 32 * bb + 31) > (q0 + wm);
            if (nm) {
                #pragma unroll
                for (int e = 0; e < 16; ++e)
                    if (kvb + (e & 3) + 8 * (e >> 2) > qrow) s[e] = -1e30f;
            }
            float pv[16];
            #pragma unroll
            for (int e = 0; e < 16; ++e) {
                pv[e] = __builtin_amdgcn_exp2f(s[e] - C2);
                ls[e & 3] += pv[e];
            }

            // ---- P -> bf16 A-frags in-register ----
            unsigned w[8];
            #pragma unroll
            for (int m = 0; m < 4; ++m) {
                w[2 * m]     = cvtpk(pv[4 * m],     pv[4 * m + 1]);
                w[2 * m + 1] = cvtpk(pv[4 * m + 2], pv[4 * m + 3]);
            }
            plswap(w[0], w[2]);   // frag g=0: words 0,2
            plswap(w[1], w[3]);   // frag g=0: words 1,3
            plswap(w[4], w[6]);   // frag g=1: words 0,2
            plswap(w[5], w[7]);   // frag g=1: words 1,3
            uint4v u0 = {w[0], w[1], w[2], w[3]};
            uint4v u1 = {w[4], w[5], w[6], w[7]};
            short8 pa0 = __builtin_bit_cast(short8, u0);
            short8 pa1 = __builtin_bit_cast(short8, u1);

            // ---- PV: A = P frags, B = V^T (col = d, k = kv) ----
            #pragma unroll
            for (int db = 0; db < 2; ++db) {
                short8 vf0 = *(const short8*)&Vt[cur][swzB(32 * db + ql, 4 * bb + hi)];
                short8 vf1 = *(const short8*)&Vt[cur][swzB(32 * db + ql, 4 * bb + 2 + hi)];
                o[db] = __builtin_amdgcn_mfma_f32_32x32x16_bf16(pa0, vf0, o[db], 0, 0, 0);
                o[db] = __builtin_amdgcn_mfma_f32_32x32x16_bf16(pa1, vf1, o[db], 0, 0, 0);
            }
        }

        if (more) {
            WRITET(cur ^ 1);
            __syncthreads();
        }
    }
#undef LOADT
#undef WRITET

    float lsum = (ls[0] + ls[1]) + (ls[2] + ls[3]);
    lsum += __shfl_xor(lsum, 32);

    // ---- epilogue: restage o (bf16) in dead Ks LDS, then full-line stores ----
    __syncthreads();                       // all waves done reading Ks/Vt
    unsigned short* Ost = &Ks[0][0];       // 16KB: [128][64], chunk ^ (row&7)
    #pragma unroll
    for (int db = 0; db < 2; ++db)
        #pragma unroll
        for (int e = 0; e < 16; ++e) {
            int row = wm + (e & 3) + 8 * (e >> 2) + 4 * hi;
            int col = db * 32 + ql;
            Ost[row * 64 + ((((col >> 3) ^ (row & 7)) & 7) << 3) + (col & 7)] =
                f2b(o[db][e]);
        }
    __syncthreads();
    #pragma unroll
    for (int p = 0; p < 4; ++p) {
        int chunk = p * 256 + tid;         // 1024 chunks = 128 rows x 8
        int row = chunk >> 3, cc = chunk & 7;
        uint4 val = *(const uint4*)&Ost[row * 64 + (((cc ^ (row & 7)) & 7) << 3)];
        *(uint4*)(pO + ((size_t)slot * 128 + row) * 64 + cc * 8) = val;
    }
    if (lane < 32)
        pL[(size_t)slot * 128 + wm + ql] = lsum;
}

// ---------------- attention combine (fixed base: plain sums) ----------------
// grid (16, 24); merges <=4 chunks of 512 kv each.
__global__ __launch_bounds__(256) void attn_combine(const unsigned short* __restrict__ pO,
                                                    const float* __restrict__ pL,
                                                    unsigned short* __restrict__ ctx) {
    const int qb  = blockIdx.x;
    const int bh  = blockIdx.y;
    const int b   = bh / 12, h = bh % 12;
    const int nch = (qb >> 2) + 1;             // ceil((qb+1)/4)
    const int slot0 = bh * 40 + chunk_ofs8(qb);
    const int tid = threadIdx.x;
    const int row = tid >> 1;
    const int col0 = (tid & 1) * 32;

    float L = 0.f;
    for (int i = 0; i < nch; ++i)
        L += pL[(size_t)(slot0 + i) * 128 + row];

    float acc[32];
    #pragma unroll
    for (int j = 0; j < 32; ++j) acc[j] = 0.f;
    for (int i = 0; i < nch; ++i) {
        const unsigned short* p = pO + ((size_t)(slot0 + i) * 128 + row) * 64 + col0;
        #pragma unroll
        for (int v4 = 0; v4 < 4; ++v4) {
            uint4 u = *(const uint4*)(p + v4 * 8);
            unsigned short t[8]; *(uint4*)t = u;
            #pragma unroll
            for (int j = 0; j < 8; ++j) acc[v4 * 8 + j] += b2f(t[j]);
        }
    }
    float inv = 1.f / L;
    unsigned short* orow = ctx + ((size_t)(b * 2048 + qb * 128 + row)) * 768 + h * 64 + col0;
    #pragma unroll
    for (int v4 = 0; v4 < 4; ++v4) {
        unsigned short t[8];
        #pragma unroll
        for (int j = 0; j < 8; ++j) t[j] = f2b(acc[v4 * 8 + j] * inv);
        *(uint4*)(orow + v4 * 8) = *(uint4*)t;
    }
}

// ---------------- fused split-K reduce + bias + residual + LayerNorm --------
__global__ __launch_bounds__(256) void resid_ln2(const float* __restrict__ X,
                                                 const float* __restrict__ P,
                                                 int nsplit,
                                                 const float* __restrict__ bv,
                                                 const float* __restrict__ gain,
                                                 const float* __restrict__ beta,
                                                 float* __restrict__ outF,
                                                 unsigned short* __restrict__ outB) {
    const int row = blockIdx.x;
    const int t   = threadIdx.x;
    const size_t off = (size_t)row * 768;
    float v[3];
    #pragma unroll
    for (int i = 0; i < 3; i++) {
        size_t c = off + t + i * 256;
        float r = X[c] + bv[t + i * 256];
        for (int p = 0; p < nsplit; ++p) r += P[(size_t)p * 3145728 + c];
        v[i] = r;
    }
    float s  = v[0] + v[1] + v[2];
    float s2 = v[0] * v[0] + v[1] * v[1] + v[2] * v[2];
    #pragma unroll
    for (int o2 = 32; o2 > 0; o2 >>= 1) {
        s  += __shfl_down(s,  o2);
        s2 += __shfl_down(s2, o2);
    }
    __shared__ float rs[4], rq[4];
    if ((t & 63) == 0) { rs[t >> 6] = s; rq[t >> 6] = s2; }
    __syncthreads();
    float S    = rs[0] + rs[1] + rs[2] + rs[3];
    float S2   = rq[0] + rq[1] + rq[2] + rq[3];
    float mean = S * (1.0f / 768.0f);
    float var  = S2 * (1.0f / 768.0f) - mean * mean;
    float inv  = rsqrtf(var + 1e-5f);
    #pragma unroll
    for (int i = 0; i < 3; i++) {
        int c   = t + i * 256;
        float y = gain[c] * (v[i] - mean) * inv + beta[c];
        if (outF) outF[off + c] = y;
        if (outB) outB[off + c] = f2b(y);
    }
}

// ---------------------------------------------------------------------------
extern "C" void kernel_launch(void* const* d_in, const int* in_sizes, int n_in,
                              void* d_out, int out_size, void* d_ws, size_t ws_size,
                              hipStream_t stream) {
    const float* x    = (const float*)d_in[0];
    const float* Wqkv = (const float*)d_in[1];
    const float* Wout = (const float*)d_in[2];
    const float* bout = (const float*)d_in[3];
    const float* W1   = (const float*)d_in[4];
    const float* b1   = (const float*)d_in[5];
    const float* W2   = (const float*)d_in[6];
    const float* b2   = (const float*)d_in[7];
    const float* g1   = (const float*)d_in[8];
    const float* be1  = (const float*)d_in[9];
    const float* g2   = (const float*)d_in[10];
    const float* be2  = (const float*)d_in[11];
    float* out = (float*)d_out;

    // workspace layout (bytes), liveness-aliased; peak 83,361,792
    char* ws = (char*)d_ws;
    unsigned short* wqkvT  = (unsigned short*)(ws + 0);         // 3.5M  ->QKV
    unsigned short* woutT  = (unsigned short*)(ws + 3538944);   // 1.2M  ->Wout
    unsigned short* w1T    = (unsigned short*)(ws + 4718592);   // 4.7M  ->W1
    unsigned short* w2T    = (unsigned short*)(ws + 9437184);   // 4.7M  ->W2
    unsigned short* xb     = (unsigned short*)(ws + 14155776);  // 6.3M  ->QKV
    unsigned short* qkvG   = (unsigned short*)(ws + 20447232);  // 18.9M ->attn_part
    unsigned short* Qg     = qkvG;
    unsigned short* Kg     = qkvG + 3145728;
    unsigned short* Vg     = qkvG + 6291456;
    unsigned short* pO     = (unsigned short*)(ws + 39321600);  // 15.7M ->combine (960 slots)
    float*          pL     = (float*)(ws + 67633152);           // 0.49M ->combine
    unsigned short* ctxb   = (unsigned short*)(ws + 14155776);  // 6.3M  combine->Wout (xb dead)
    float*          WoutP  = (float*)(ws + 39321600);           // 3x12.6M Wout->LN1; ends 77,070,336
    float*          h      = (float*)(ws + 20447232);           // 12.6M LN1->LN2 (qkvG dead)
    unsigned short* hb     = (unsigned short*)(ws + 77070336);  // 6.3M  LN1->W1; ends 83,361,792
    unsigned short* ffb    = (unsigned short*)(ws + 39321600);  // 25.2M W1->W2 (WoutP dead)
    float*          W2P    = (float*)(ws + 64487424);           // 2x12.6M W2->LN2; ends 77,070,336

    // 1) fused prepass
    prep_all<<<9984, 256, 0, stream>>>(x, xb, Wqkv, wqkvT, Wout, woutT, W1, w1T, W2, w2T);
    // 2) QKV projection -> Q/K/V [bh][s][64] bf16 (Q pre-scaled by QSC)
    gemm_bf16<<<dim3(18, 32), 256, 0, stream>>>(xb, wqkvT, nullptr, nullptr, qkvG,
                                                4096, 2304, 768, 0, 1, 768);
    // 3) kv-split flash attention (512-wide chunks) + combine -> ctx bf16
    attn_part<<<dim3(40, 24), 256, 0, stream>>>(Qg, Kg, Vg, pO, pL);
    attn_combine<<<dim3(16, 24), 256, 0, stream>>>(pO, pL, ctxb);
    // 4) out projection, split-K=3 -> fp32 partials
    gemm_bf16<<<dim3(6, 32, 3), 256, 0, stream>>>(ctxb, woutT, nullptr, WoutP, nullptr,
                                                  4096, 768, 768, 0, 2, 256);
    // 5) h = LN(x + sum(WoutP) + bout) -> fp32 + bf16
    resid_ln2<<<4096, 256, 0, stream>>>(x, WoutP, 3, bout, g1, be1, h, hb);
    // 6) ff = relu(h @ W1 + b1) -> bf16
    gemm_bf16<<<dim3(24, 32), 256, 0, stream>>>(hb, w1T, b1, nullptr, ffb,
                                                4096, 3072, 768, 1, 0, 768);
    // 7) ff2 partials = ff @ W2 (split-K=2)
    gemm_bf16<<<dim3(6, 32, 2), 256, 0, stream>>>(ffb, w2T, nullptr, W2P, nullptr,
                                                  4096, 768, 3072, 0, 2, 1536);
    // 8) out = LN(h + sum(W2P) + b2) -> fp32
    resid_ln2<<<4096, 256, 0, stream>>>(h, W2P, 2, b2, g2, be2, out, nullptr);
}